// Round 1
// baseline (205.212 us; speedup 1.0000x reference)
//
#include <hip/hip_runtime.h>
#include <math.h>

#define NN 648      // code length / variables
#define EE 1944     // edges
#define NCHK 324    // checks (DV*M_PER = 3*108), each = 6 consecutive edges
#define BATCH 2048
#define CLAMPV 0.999999f
#define BS 256

// ---------------------------------------------------------------------------
// Structure extraction (re-run every call; inputs restored pristine each time)
// ---------------------------------------------------------------------------

// M_out is [N,E] = M_ev.T : exactly one nonzero per column e, at row var_of[e].
// Each variable appears exactly once per permutation layer (e/648), so
// varEdge[n*3 + layer] is written exactly once, race-free.
__global__ __launch_bounds__(BS) void extract_struct(
    const float* __restrict__ M_out,
    int* __restrict__ var_of, int* __restrict__ varEdge) {
    int idx = blockIdx.x * BS + threadIdx.x;
    if (idx >= NN * EE) return;
    int n = idx / EE;
    int e = idx - n * EE;
    if (M_out[idx] != 0.0f) {
        var_of[e] = n;
        varEdge[n * 3 + e / NN] = e;
    }
}

// Per edge: 2 extrinsic same-var neighbors + their weights in W1/W3/W5/W7,
// bias_matrix value. Per var: W9 and M_out values for its 3 edges.
__global__ __launch_bounds__(BS) void extract_weights(
    const float* __restrict__ Mo, const float* __restrict__ bias_matrix,
    const float* __restrict__ W1, const float* __restrict__ W3,
    const float* __restrict__ W5, const float* __restrict__ W7,
    const float* __restrict__ W9,
    const int* __restrict__ var_of, const int* __restrict__ varEdge,
    int* __restrict__ nb, float* __restrict__ bmv,
    float* __restrict__ w1v, float* __restrict__ w3v,
    float* __restrict__ w5v, float* __restrict__ w7v,
    float* __restrict__ w9v, float* __restrict__ moutv) {
    int tid = blockIdx.x * BS + threadIdx.x;
    if (tid < EE) {
        int e = tid;
        int n = var_of[e];
        int e0 = varEdge[3 * n], e1 = varEdge[3 * n + 1], e2 = varEdge[3 * n + 2];
        int ea, eb;
        if (e == e0)      { ea = e1; eb = e2; }
        else if (e == e1) { ea = e0; eb = e2; }
        else              { ea = e0; eb = e1; }
        nb[2 * e] = ea; nb[2 * e + 1] = eb;
        size_t row = (size_t)e * EE;
        w1v[2 * e] = W1[row + ea]; w1v[2 * e + 1] = W1[row + eb];
        w3v[2 * e] = W3[row + ea]; w3v[2 * e + 1] = W3[row + eb];
        w5v[2 * e] = W5[row + ea]; w5v[2 * e + 1] = W5[row + eb];
        w7v[2 * e] = W7[row + ea]; w7v[2 * e + 1] = W7[row + eb];
        bmv[e] = bias_matrix[(size_t)n * EE + e];
    } else if (tid < EE + NN) {
        int n = tid - EE;
        for (int k = 0; k < 3; k++) {
            int e = varEdge[3 * n + k];
            w9v[3 * n + k]   = W9[(size_t)n * EE + e];
            moutv[3 * n + k] = Mo[(size_t)n * EE + e];
        }
    }
}

// ---------------------------------------------------------------------------
// Main BP kernel: one block per batch row, all state in LDS
// ---------------------------------------------------------------------------

__device__ __forceinline__ float tanh_half(float x) { return tanhf(0.5f * x); }
__device__ __forceinline__ float sigm(float s) { return 1.0f / (1.0f + expf(-s)); }

// Extrinsic check-node product, exactly matching reference semantics:
// product over nonzero extrinsic terms; 0 only if no nonzero extrinsic term.
// Then clamp and 2*arctanh.
__device__ __forceinline__ void cn_pass(const float* __restrict__ te,
                                        float* __restrict__ tl, int tid) {
    for (int c = tid; c < NCHK; c += BS) {
        const int base = 6 * c;
        float v[6];
        #pragma unroll
        for (int k = 0; k < 6; k++) v[k] = te[base + k];
        float P = 1.0f; int cz = 0;
        #pragma unroll
        for (int k = 0; k < 6; k++) {
            if (v[k] == 0.0f) cz++; else P *= v[k];
        }
        #pragma unroll
        for (int k = 0; k < 6; k++) {
            float a = v[k];
            float ext;
            if (a != 0.0f) ext = (cz >= 5) ? 0.0f : P / a;   // extrinsic nz count = 5-cz
            else           ext = (cz >= 6) ? 0.0f : P;       // extrinsic nz count = 6-cz
            ext = fminf(fmaxf(ext, -CLAMPV), CLAMPV);
            tl[base + k] = logf((1.0f + ext) / (1.0f - ext)); // = 2*arctanh(ext)
        }
    }
}

__device__ __forceinline__ void marg_out(float* __restrict__ dst,
        const float* __restrict__ tl, const float* __restrict__ llr_s,
        const int* __restrict__ varEdge, const float* __restrict__ moutv, int tid) {
    for (int n = tid; n < NN; n += BS) {
        float s = llr_s[n];
        #pragma unroll
        for (int k = 0; k < 3; k++) s += moutv[3 * n + k] * tl[varEdge[3 * n + k]];
        dst[n] = sigm(s);
    }
}

__global__ __launch_bounds__(BS) void bp_main(
    const float* __restrict__ x,
    const int* __restrict__ var_of, const int* __restrict__ varEdge,
    const int* __restrict__ nb, const float* __restrict__ bmv,
    const float* __restrict__ w1v, const float* __restrict__ w3v,
    const float* __restrict__ w5v, const float* __restrict__ w7v,
    const float* __restrict__ w9v, const float* __restrict__ moutv,
    float* __restrict__ out) {
    __shared__ float llr_s[NN];
    __shared__ float te[EE];
    __shared__ float tl[EE];
    const int b = blockIdx.x;
    const int tid = threadIdx.x;

    const float* xr = x + (size_t)b * NN;
    for (int n = tid; n < NN; n += BS) llr_s[n] = xr[n];
    __syncthreads();

    // iteration 0: te[e] = tanh(0.5 * llr[var_of[e]])
    for (int e = tid; e < EE; e += BS) te[e] = tanh_half(llr_s[var_of[e]]);
    __syncthreads();
    cn_pass(te, tl, tid);
    __syncthreads();
    // out1 -> chunk 4 (return order: out5,out4,out3,out2,out1)
    marg_out(out + ((size_t)(4 * BATCH) + b) * NN, tl, llr_s, varEdge, moutv, tid);

    const float* wvs[4] = {w1v, w3v, w5v, w7v};
    for (int L = 0; L < 4; L++) {
        const float* __restrict__ wv = wvs[L];
        // VN update: pre = W t_ext + llr gather ; te = tanh(0.5*pre)
        for (int e = tid; e < EE; e += BS) {
            float pre = wv[2 * e] * tl[nb[2 * e]]
                      + wv[2 * e + 1] * tl[nb[2 * e + 1]]
                      + bmv[e] * llr_s[var_of[e]];
            te[e] = tanh_half(pre);
        }
        __syncthreads();   // also guards previous marg_out reads of tl
        cn_pass(te, tl, tid);
        __syncthreads();
        if (L < 3) {
            // out2->chunk3, out3->chunk2, out4->chunk1
            marg_out(out + ((size_t)((3 - L) * BATCH) + b) * NN, tl, llr_s, varEdge, moutv, tid);
        } else {
            // out5 -> chunk 0: t@W9.T + llr (B4 = I)
            for (int n = tid; n < NN; n += BS) {
                float s = llr_s[n];
                #pragma unroll
                for (int k = 0; k < 3; k++) s += w9v[3 * n + k] * tl[varEdge[3 * n + k]];
                out[(size_t)b * NN + n] = sigm(s);
            }
        }
    }
}

// ---------------------------------------------------------------------------
extern "C" void kernel_launch(void* const* d_in, const int* in_sizes, int n_in,
                              void* d_out, int out_size, void* d_ws, size_t ws_size,
                              hipStream_t stream) {
    const float* x           = (const float*)d_in[0];
    // d_in[1] = M_first, d_in[2] = M_cn : patterns implied by chk structure (6 consecutive edges/check)
    const float* M_out       = (const float*)d_in[3];
    const float* bias_matrix = (const float*)d_in[4];
    const float* W1          = (const float*)d_in[5];
    const float* W3          = (const float*)d_in[6];
    const float* W5          = (const float*)d_in[7];
    const float* W7          = (const float*)d_in[8];
    const float* W9          = (const float*)d_in[9];
    // d_in[10..14] = B0..B4 (identity by construction; llr @ I = llr)
    float* out = (float*)d_out;

    char* ws = (char*)d_ws;
    int*   var_of  = (int*)ws;   ws += EE * 4;
    int*   varEdge = (int*)ws;   ws += NN * 3 * 4;
    int*   nb      = (int*)ws;   ws += EE * 2 * 4;
    float* bmv     = (float*)ws; ws += EE * 4;
    float* w1v     = (float*)ws; ws += EE * 2 * 4;
    float* w3v     = (float*)ws; ws += EE * 2 * 4;
    float* w5v     = (float*)ws; ws += EE * 2 * 4;
    float* w7v     = (float*)ws; ws += EE * 2 * 4;
    float* w9v     = (float*)ws; ws += NN * 3 * 4;
    float* moutv   = (float*)ws; ws += NN * 3 * 4;

    const int totA = NN * EE;
    extract_struct<<<(totA + BS - 1) / BS, BS, 0, stream>>>(M_out, var_of, varEdge);
    extract_weights<<<(EE + NN + BS - 1) / BS, BS, 0, stream>>>(
        M_out, bias_matrix, W1, W3, W5, W7, W9,
        var_of, varEdge, nb, bmv, w1v, w3v, w5v, w7v, w9v, moutv);
    bp_main<<<BATCH, BS, 0, stream>>>(
        x, var_of, varEdge, nb, bmv, w1v, w3v, w5v, w7v, w9v, moutv, out);
}

// Round 3
// 186.061 us; speedup vs baseline: 1.1029x; 1.1029x over previous
//
#include <hip/hip_runtime.h>
#include <math.h>

#define NN 648      // code length / variables
#define EE 1944     // edges
#define NCHK 324    // checks, each = 6 consecutive edges
#define BATCH 2048
#define CLAMPV 0.999999f
#define BS 256
#define NE_IT 8     // ceil(EE/BS)

// ---------------------------------------------------------------------------
// Fast transcendentals (hardware v_exp_f32 / v_log_f32 / v_rcp_f32).
// CRITICAL: tanh_half must return 0 IFF x==0 — zero-ness gates the reference's
// cn_update nz-mask semantics (discrete behavior, not a precision matter).
// The exp-based formula returns exact 0 for |x| < ~2e-7 (E+1 rounds to 2.0,
// rcp(2)=0.5 exact) -> use a Taylor path for small |x| instead.
// ---------------------------------------------------------------------------
__device__ __forceinline__ float rcp_fast(float x) { return __builtin_amdgcn_rcpf(x); }

__device__ __forceinline__ float tanh_half(float x) {
    float a = fabsf(x);
    float u = 0.5f * x;
    float small = u * (1.0f - 0.33333334f * u * u);   // tanh(u) ~ u - u^3/3, |u|<=2^-6
    float E = __expf(a);                  // inf for large a -> r = 1, correct saturation
    float r = 1.0f - 2.0f * rcp_fast(E + 1.0f);
    float big = copysignf(r, x);
    return (a < 0.03125f) ? small : big;
}

__device__ __forceinline__ float two_atanh_clamped(float e) {
    e = fminf(fmaxf(e, -CLAMPV), CLAMPV);
    float r = (1.0f + e) * rcp_fast(1.0f - e);   // 1-e >= 1e-6 after clamp
    return 0.6931471805599453f * __log2f(r);
}

__device__ __forceinline__ float sigm(float s) {
    return rcp_fast(1.0f + __expf(-s));
}

// ---------------------------------------------------------------------------
// Structure extraction (re-run every call; inputs restored pristine each time)
// M_out is [N,E] = M_ev.T: one nonzero (==1.0) per column e, at row var_of[e].
// Each var appears once per permutation layer (layer = e/NN) -> race-free.
// float4-vectorized: EE % 4 == 0, so a float4 never crosses a row boundary.
// ---------------------------------------------------------------------------
__global__ __launch_bounds__(BS) void extract_struct(
    const float4* __restrict__ M_out4,
    int* __restrict__ var_of, int* __restrict__ varEdge) {
    int t = blockIdx.x * BS + threadIdx.x;
    if (t >= NN * EE / 4) return;
    float4 v = M_out4[t];
    int flat = t * 4;
    int n = flat / EE;
    int e = flat - n * EE;
    if (v.x != 0.0f) { var_of[e]     = n; varEdge[n * 3 + (e)     / NN] = e;     }
    if (v.y != 0.0f) { var_of[e + 1] = n; varEdge[n * 3 + (e + 1) / NN] = e + 1; }
    if (v.z != 0.0f) { var_of[e + 2] = n; varEdge[n * 3 + (e + 2) / NN] = e + 2; }
    if (v.w != 0.0f) { var_of[e + 3] = n; varEdge[n * 3 + (e + 3) / NN] = e + 3; }
}

// Per edge: 2 extrinsic same-var neighbors + their W weights (packed float2).
// Per var: W9 values for its 3 edges. (bias_matrix / M_out values are 1.0 by
// construction of M_ev, so no value extraction needed for them.)
__global__ __launch_bounds__(BS) void extract_weights(
    const float* __restrict__ W1, const float* __restrict__ W3,
    const float* __restrict__ W5, const float* __restrict__ W7,
    const float* __restrict__ W9,
    const int* __restrict__ var_of, const int* __restrict__ varEdge,
    int2* __restrict__ nb,
    float2* __restrict__ w1v, float2* __restrict__ w3v,
    float2* __restrict__ w5v, float2* __restrict__ w7v,
    float* __restrict__ w9v) {
    int tid = blockIdx.x * BS + threadIdx.x;
    if (tid < EE) {
        int e = tid;
        int n = var_of[e];
        int e0 = varEdge[3 * n], e1 = varEdge[3 * n + 1], e2 = varEdge[3 * n + 2];
        int ea, eb;
        if (e == e0)      { ea = e1; eb = e2; }
        else if (e == e1) { ea = e0; eb = e2; }
        else              { ea = e0; eb = e1; }
        nb[e] = make_int2(ea, eb);
        size_t row = (size_t)e * EE;
        w1v[e] = make_float2(W1[row + ea], W1[row + eb]);
        w3v[e] = make_float2(W3[row + ea], W3[row + eb]);
        w5v[e] = make_float2(W5[row + ea], W5[row + eb]);
        w7v[e] = make_float2(W7[row + ea], W7[row + eb]);
    } else if (tid < EE + NN) {
        int n = tid - EE;
        #pragma unroll
        for (int k = 0; k < 3; k++) {
            int e = varEdge[3 * n + k];
            w9v[3 * n + k] = W9[(size_t)n * EE + e];
        }
    }
}

// ---------------------------------------------------------------------------
// Main BP kernel: one block per batch row, all state in LDS (18.1 KB -> 8/CU)
// ---------------------------------------------------------------------------

// One edge per thread. P = product of nonzero check members, cz = zero count;
// extrinsic = P/a with reference's skip-zero / any_nz semantics.
__device__ __forceinline__ void cn_pass(const float* __restrict__ te,
                                        float* __restrict__ tl, int tid) {
    #pragma unroll
    for (int i = 0; i < NE_IT; i++) {
        int e = tid + i * BS;
        if (e >= EE) break;
        int c = (int)((unsigned)e / 6u);
        const float2* p2 = (const float2*)(te + 6 * c);   // 24c bytes: 8-aligned
        float2 v01 = p2[0], v23 = p2[1], v45 = p2[2];
        float a = te[e];
        float P = 1.0f; int cz = 0;
        float vv[6] = {v01.x, v01.y, v23.x, v23.y, v45.x, v45.y};
        #pragma unroll
        for (int k = 0; k < 6; k++) {
            if (vv[k] == 0.0f) cz++; else P *= vv[k];
        }
        float ext;
        if (a != 0.0f) ext = (cz >= 5) ? 0.0f : P * rcp_fast(a);
        else           ext = (cz >= 6) ? 0.0f : P;
        tl[e] = two_atanh_clamped(ext);
    }
}

// Marginal + sigmoid. M_out values are 1.0 -> plain sum over the var's edges.
__device__ __forceinline__ void marg_out(float* __restrict__ dst,
        const float* __restrict__ tl, const float* __restrict__ llr_s,
        const int* __restrict__ varEdge, int tid) {
    for (int n = tid; n < NN; n += BS) {
        float s = llr_s[n] + tl[varEdge[3 * n]] + tl[varEdge[3 * n + 1]]
                           + tl[varEdge[3 * n + 2]];
        dst[n] = sigm(s);
    }
}

__global__ __launch_bounds__(BS, 8) void bp_main(
    const float* __restrict__ x,
    const int* __restrict__ var_of, const int* __restrict__ varEdge,
    const int2* __restrict__ nb,
    const float2* __restrict__ w1v, const float2* __restrict__ w3v,
    const float2* __restrict__ w5v, const float2* __restrict__ w7v,
    const float* __restrict__ w9v,
    float* __restrict__ out) {
    __shared__ __align__(16) float llr_s[NN];
    __shared__ __align__(16) float te[EE];
    __shared__ __align__(16) float tl[EE];
    const int b = blockIdx.x;
    const int tid = threadIdx.x;

    const float* xr = x + (size_t)b * NN;
    for (int n = tid; n < NN; n += BS) llr_s[n] = xr[n];
    __syncthreads();

    // Per-edge LLR gather, constant across layers (bias_matrix values == 1.0):
    // lb[i] = llr[var_of[e]].  Iteration 0: te = tanh(0.5*lb).
    float lb[NE_IT];
    #pragma unroll
    for (int i = 0; i < NE_IT; i++) {
        int e = tid + i * BS;
        if (e < EE) {
            lb[i] = llr_s[var_of[e]];
            te[e] = tanh_half(lb[i]);
        }
    }
    __syncthreads();
    cn_pass(te, tl, tid);
    __syncthreads();
    // out1 -> chunk 4 (return order: out5,out4,out3,out2,out1)
    marg_out(out + ((size_t)(4 * BATCH) + b) * NN, tl, llr_s, varEdge, tid);

    const float2* wvs[4] = {w1v, w3v, w5v, w7v};
    for (int L = 0; L < 4; L++) {
        const float2* __restrict__ wv = wvs[L];
        // VN update: pre = w.x*tl[ea] + w.y*tl[eb] + llr[var];  te = tanh(pre/2)
        #pragma unroll
        for (int i = 0; i < NE_IT; i++) {
            int e = tid + i * BS;
            if (e < EE) {
                int2 nn = nb[e];
                float2 w = wv[e];
                float pre = w.x * tl[nn.x] + w.y * tl[nn.y] + lb[i];
                te[e] = tanh_half(pre);
            }
        }
        __syncthreads();   // te visible; also fences prior marg_out tl reads
        cn_pass(te, tl, tid);
        __syncthreads();
        if (L < 3) {
            // out2->chunk3, out3->chunk2, out4->chunk1
            marg_out(out + ((size_t)((3 - L) * BATCH) + b) * NN, tl, llr_s, varEdge, tid);
        } else {
            // out5 -> chunk 0: sigmoid(t@W9.T + llr)   (B4 = I)
            for (int n = tid; n < NN; n += BS) {
                float s = llr_s[n]
                        + w9v[3 * n]     * tl[varEdge[3 * n]]
                        + w9v[3 * n + 1] * tl[varEdge[3 * n + 1]]
                        + w9v[3 * n + 2] * tl[varEdge[3 * n + 2]];
                out[(size_t)b * NN + n] = sigm(s);
            }
        }
    }
}

// ---------------------------------------------------------------------------
extern "C" void kernel_launch(void* const* d_in, const int* in_sizes, int n_in,
                              void* d_out, int out_size, void* d_ws, size_t ws_size,
                              hipStream_t stream) {
    const float* x     = (const float*)d_in[0];
    const float* M_out = (const float*)d_in[3];
    const float* W1    = (const float*)d_in[5];
    const float* W3    = (const float*)d_in[6];
    const float* W5    = (const float*)d_in[7];
    const float* W7    = (const float*)d_in[8];
    const float* W9    = (const float*)d_in[9];
    // d_in[1]=M_first, d_in[2]=M_cn (patterns implied by check structure),
    // d_in[4]=bias_matrix (values 1.0), d_in[10..14]=B0..B4 (identity).
    float* out = (float*)d_out;

    char* ws = (char*)d_ws;
    int2*   nb      = (int2*)ws;   ws += EE * 8;
    float2* w1v     = (float2*)ws; ws += EE * 8;
    float2* w3v     = (float2*)ws; ws += EE * 8;
    float2* w5v     = (float2*)ws; ws += EE * 8;
    float2* w7v     = (float2*)ws; ws += EE * 8;
    int*    var_of  = (int*)ws;    ws += EE * 4;
    int*    varEdge = (int*)ws;    ws += NN * 3 * 4;
    float*  w9v     = (float*)ws;  ws += NN * 3 * 4;

    const int tot4 = NN * EE / 4;
    extract_struct<<<(tot4 + BS - 1) / BS, BS, 0, stream>>>(
        (const float4*)M_out, var_of, varEdge);
    extract_weights<<<(EE + NN + BS - 1) / BS, BS, 0, stream>>>(
        W1, W3, W5, W7, W9, var_of, varEdge, nb, w1v, w3v, w5v, w7v, w9v);
    bp_main<<<BATCH, BS, 0, stream>>>(
        x, var_of, varEdge, nb, w1v, w3v, w5v, w7v, w9v, out);
}

// Round 4
// 177.814 us; speedup vs baseline: 1.1541x; 1.0464x over previous
//
#include <hip/hip_runtime.h>
#include <math.h>

#define NN 648      // code length / variables
#define EE 1944     // edges
#define BATCH 2048
#define BS 256
#define NE_IT 8     // ceil(EE/BS)
#define TL_CLAMP 14.508648f   // 2*atanh(0.999999)

// ---------------------------------------------------------------------------
// Fast transcendentals (hardware v_exp_f32 / v_log_f32 / v_rcp_f32).
// CRITICAL: tanh_half returns 0 IFF x==0 — zero-ness gates the reference's
// cn_update nz-mask semantics (R2 lesson: exp path flushes |x|<~2e-7 -> Taylor
// small path keeps tiny nonzeros nonzero).
// ---------------------------------------------------------------------------
__device__ __forceinline__ float rcp_fast(float x) { return __builtin_amdgcn_rcpf(x); }

__device__ __forceinline__ float tanh_half(float x) {
    // tanh(x/2) = 1 - 2/(e^x + 1): sign-correct for both signs, saturates to
    // exactly +/-1 at |x| large (E=inf -> 1; E=0 -> -1).
    float E = __expf(x);
    float big = 1.0f - 2.0f * rcp_fast(E + 1.0f);
    float u = 0.5f * x;
    float small = u * (1.0f - 0.33333334f * u * u);   // |u|<=2^-6, err ~6e-10
    return (fabsf(x) < 0.03125f) ? small : big;
}

__device__ __forceinline__ float sigm(float s) {
    return rcp_fast(1.0f + __expf(-s));
}

// ---------------------------------------------------------------------------
// Structure extraction (re-run every call; inputs restored pristine each time)
// M_out is [N,E] = M_ev.T: one nonzero (==1.0) per column e, at row var_of[e].
// Each var appears once per permutation layer (layer = e/NN) -> race-free.
// ---------------------------------------------------------------------------
__global__ __launch_bounds__(BS) void extract_struct(
    const float4* __restrict__ M_out4,
    int* __restrict__ var_of, int* __restrict__ varEdge) {
    int t = blockIdx.x * BS + threadIdx.x;
    if (t >= NN * EE / 4) return;
    float4 v = M_out4[t];
    int flat = t * 4;
    int n = flat / EE;
    int e = flat - n * EE;
    if (v.x != 0.0f) { var_of[e]     = n; varEdge[n * 3 + (e)     / NN] = e;     }
    if (v.y != 0.0f) { var_of[e + 1] = n; varEdge[n * 3 + (e + 1) / NN] = e + 1; }
    if (v.z != 0.0f) { var_of[e + 2] = n; varEdge[n * 3 + (e + 2) / NN] = e + 2; }
    if (v.w != 0.0f) { var_of[e + 3] = n; varEdge[n * 3 + (e + 3) / NN] = e + 3; }
}

// Per edge: 2 extrinsic same-var neighbors + their W weights (packed float2).
// Per var: W9 values for its 3 edges. (bias_matrix / M_out values are 1.0.)
__global__ __launch_bounds__(BS) void extract_weights(
    const float* __restrict__ W1, const float* __restrict__ W3,
    const float* __restrict__ W5, const float* __restrict__ W7,
    const float* __restrict__ W9,
    const int* __restrict__ var_of, const int* __restrict__ varEdge,
    int2* __restrict__ nb,
    float2* __restrict__ w1v, float2* __restrict__ w3v,
    float2* __restrict__ w5v, float2* __restrict__ w7v,
    float* __restrict__ w9v) {
    int tid = blockIdx.x * BS + threadIdx.x;
    if (tid < EE) {
        int e = tid;
        int n = var_of[e];
        int e0 = varEdge[3 * n], e1 = varEdge[3 * n + 1], e2 = varEdge[3 * n + 2];
        int ea, eb;
        if (e == e0)      { ea = e1; eb = e2; }
        else if (e == e1) { ea = e0; eb = e2; }
        else              { ea = e0; eb = e1; }
        nb[e] = make_int2(ea, eb);
        size_t row = (size_t)e * EE;
        w1v[e] = make_float2(W1[row + ea], W1[row + eb]);
        w3v[e] = make_float2(W3[row + ea], W3[row + eb]);
        w5v[e] = make_float2(W5[row + ea], W5[row + eb]);
        w7v[e] = make_float2(W7[row + ea], W7[row + eb]);
    } else if (tid < EE + NN) {
        int n = tid - EE;
        #pragma unroll
        for (int k = 0; k < 3; k++) {
            int e = varEdge[3 * n + k];
            w9v[3 * n + k] = W9[(size_t)n * EE + e];
        }
    }
}

// ---------------------------------------------------------------------------
// Main BP kernel: one block per batch row, all state in LDS (18.1 KB -> 8/CU)
// ---------------------------------------------------------------------------

// Check-node pass, two-log form:
//   Q = prod of all 6 members; ext = Q/a; 2*atanh(ext) = ln((a+Q)/(a-Q))
//     = ln2 * (log2|a+Q| - log2|a-Q|), clamped at +/-2*atanh(0.999999).
// Saturation: a-+Q == 0 -> +/-inf -> clamp == ref's e-domain clamp.
// Q==0 (an exact-zero member, or full underflow) -> rare fallback implementing
// the reference's skip-zero extrinsic semantics exactly.
__device__ __forceinline__ void cn_pass(const float* __restrict__ te,
                                        float* __restrict__ tl, int tid) {
    #pragma unroll
    for (int i = 0; i < NE_IT; i++) {
        int e = tid + i * BS;
        if (e >= EE) break;
        int c = (int)((unsigned)e / 6u);
        const float2* p2 = (const float2*)(te + 6 * c);   // 24c bytes: 8-aligned
        float2 v01 = p2[0], v23 = p2[1], v45 = p2[2];
        float a = te[e];
        float Q = ((v01.x * v01.y) * (v23.x * v23.y)) * (v45.x * v45.y);
        float tlv;
        if (__builtin_expect(Q != 0.0f, 1)) {
            float s = a + Q, d = a - Q;
            tlv = 0.6931472f * (__log2f(fabsf(s)) - __log2f(fabsf(d)));
            tlv = fminf(fmaxf(tlv, -TL_CLAMP), TL_CLAMP);
        } else {
            float vv[6] = {v01.x, v01.y, v23.x, v23.y, v45.x, v45.y};
            float P = 1.0f; int cz = 0;
            #pragma unroll
            for (int k = 0; k < 6; k++) {
                if (vv[k] == 0.0f) cz++; else P *= vv[k];
            }
            float ext;
            if (a != 0.0f) ext = (cz >= 5) ? 0.0f : P * rcp_fast(a);
            else           ext = (cz >= 6) ? 0.0f : P;
            ext = fminf(fmaxf(ext, -0.999999f), 0.999999f);
            tlv = 0.6931472f * __log2f((1.0f + ext) * rcp_fast(1.0f - ext));
        }
        tl[e] = tlv;
    }
}

// Marginal + sigmoid. M_out values are 1.0 -> plain sum over the var's edges.
__device__ __forceinline__ void marg_out(float* __restrict__ dst,
        const float* __restrict__ tl, const float* __restrict__ llr_s,
        const int* __restrict__ varEdge, int tid) {
    for (int n = tid; n < NN; n += BS) {
        float s = llr_s[n] + tl[varEdge[3 * n]] + tl[varEdge[3 * n + 1]]
                           + tl[varEdge[3 * n + 2]];
        dst[n] = sigm(s);
    }
}

__global__ __launch_bounds__(BS, 8) void bp_main(
    const float* __restrict__ x,
    const int* __restrict__ var_of, const int* __restrict__ varEdge,
    const int2* __restrict__ nb,
    const float2* __restrict__ w1v, const float2* __restrict__ w3v,
    const float2* __restrict__ w5v, const float2* __restrict__ w7v,
    const float* __restrict__ w9v,
    float* __restrict__ out) {
    __shared__ __align__(16) float llr_s[NN];
    __shared__ __align__(16) float te[EE];
    __shared__ __align__(16) float tl[EE];
    const int b = blockIdx.x;
    const int tid = threadIdx.x;

    const float* xr = x + (size_t)b * NN;
    for (int n = tid; n < NN; n += BS) llr_s[n] = xr[n];
    __syncthreads();

    // Loop-invariant per-thread state, cached once:
    //   lb[i]   = llr[var_of[e]]  (bias_matrix values == 1.0, B0..B3 == I)
    //   pA/pB   = LDS pointers to the 2 extrinsic same-var neighbors' tl
    // Iteration 0: te = tanh(0.5*lb).
    float lb[NE_IT];
    const float* pA[NE_IT];
    const float* pB[NE_IT];
    #pragma unroll
    for (int i = 0; i < NE_IT; i++) {
        int e = tid + i * BS;
        if (e < EE) {
            lb[i] = llr_s[var_of[e]];
            int2 nn = nb[e];
            pA[i] = tl + nn.x;
            pB[i] = tl + nn.y;
            te[e] = tanh_half(lb[i]);
        } else {
            lb[i] = 0.0f; pA[i] = tl; pB[i] = tl;
        }
    }
    __syncthreads();
    cn_pass(te, tl, tid);
    __syncthreads();
    // out1 -> chunk 4 (return order: out5,out4,out3,out2,out1)
    marg_out(out + ((size_t)(4 * BATCH) + b) * NN, tl, llr_s, varEdge, tid);

    const float2* wvs[4] = {w1v, w3v, w5v, w7v};
    for (int L = 0; L < 4; L++) {
        const float2* __restrict__ wv = wvs[L];
        // VN update: pre = w.x*tl[ea] + w.y*tl[eb] + llr[var];  te = tanh(pre/2)
        #pragma unroll
        for (int i = 0; i < NE_IT; i++) {
            int e = tid + i * BS;
            if (e < EE) {
                float2 w = wv[e];
                float pre = fmaf(w.x, *pA[i], fmaf(w.y, *pB[i], lb[i]));
                te[e] = tanh_half(pre);
            }
        }
        __syncthreads();   // te visible; also fences prior marg_out tl reads
        cn_pass(te, tl, tid);
        __syncthreads();
        if (L < 3) {
            // out2->chunk3, out3->chunk2, out4->chunk1
            marg_out(out + ((size_t)((3 - L) * BATCH) + b) * NN, tl, llr_s, varEdge, tid);
        } else {
            // out5 -> chunk 0: sigmoid(t@W9.T + llr)   (B4 = I)
            for (int n = tid; n < NN; n += BS) {
                float s = llr_s[n]
                        + w9v[3 * n]     * tl[varEdge[3 * n]]
                        + w9v[3 * n + 1] * tl[varEdge[3 * n + 1]]
                        + w9v[3 * n + 2] * tl[varEdge[3 * n + 2]];
                out[(size_t)b * NN + n] = sigm(s);
            }
        }
    }
}

// ---------------------------------------------------------------------------
extern "C" void kernel_launch(void* const* d_in, const int* in_sizes, int n_in,
                              void* d_out, int out_size, void* d_ws, size_t ws_size,
                              hipStream_t stream) {
    const float* x     = (const float*)d_in[0];
    const float* M_out = (const float*)d_in[3];
    const float* W1    = (const float*)d_in[5];
    const float* W3    = (const float*)d_in[6];
    const float* W5    = (const float*)d_in[7];
    const float* W7    = (const float*)d_in[8];
    const float* W9    = (const float*)d_in[9];
    // d_in[1]=M_first, d_in[2]=M_cn (patterns implied by check structure),
    // d_in[4]=bias_matrix (values 1.0), d_in[10..14]=B0..B4 (identity).
    float* out = (float*)d_out;

    char* ws = (char*)d_ws;
    int2*   nb      = (int2*)ws;   ws += EE * 8;
    float2* w1v     = (float2*)ws; ws += EE * 8;
    float2* w3v     = (float2*)ws; ws += EE * 8;
    float2* w5v     = (float2*)ws; ws += EE * 8;
    float2* w7v     = (float2*)ws; ws += EE * 8;
    int*    var_of  = (int*)ws;    ws += EE * 4;
    int*    varEdge = (int*)ws;    ws += NN * 3 * 4;
    float*  w9v     = (float*)ws;  ws += NN * 3 * 4;

    const int tot4 = NN * EE / 4;
    extract_struct<<<(tot4 + BS - 1) / BS, BS, 0, stream>>>(
        (const float4*)M_out, var_of, varEdge);
    extract_weights<<<(EE + NN + BS - 1) / BS, BS, 0, stream>>>(
        W1, W3, W5, W7, W9, var_of, varEdge, nb, w1v, w3v, w5v, w7v, w9v);
    bp_main<<<BATCH, BS, 0, stream>>>(
        x, var_of, varEdge, nb, w1v, w3v, w5v, w7v, w9v, out);
}

// Round 5
// 175.684 us; speedup vs baseline: 1.1681x; 1.0121x over previous
//
#include <hip/hip_runtime.h>
#include <math.h>

#define NN 648      // code length / variables
#define EE 1944     // edges
#define NP 972      // edge pairs (2 per thread-item; 3 pairs per check)
#define BATCH 2048
#define BS 256
#define NP_IT 4     // ceil(NP/BS)
#define TL_CLAMP 14.508648f   // 2*atanh(0.999999)

// ---------------------------------------------------------------------------
// Fast transcendentals (hardware v_exp_f32 / v_log_f32 / v_rcp_f32).
// CRITICAL: tanh_half returns 0 IFF x==0 — zero-ness gates the reference's
// cn_update nz-mask semantics (R2 lesson: exp path flushes |x|<~2e-7 -> Taylor
// small path keeps tiny nonzeros nonzero).
// ---------------------------------------------------------------------------
__device__ __forceinline__ float rcp_fast(float x) { return __builtin_amdgcn_rcpf(x); }

__device__ __forceinline__ float tanh_half(float x) {
    // tanh(x/2) = 1 - 2/(e^x + 1): sign-correct, saturates exactly to +/-1.
    float E = __expf(x);
    float big = 1.0f - 2.0f * rcp_fast(E + 1.0f);
    float u = 0.5f * x;
    float small = u * (1.0f - 0.33333334f * u * u);   // |u|<=2^-6, err ~6e-10
    return (fabsf(x) < 0.03125f) ? small : big;
}

__device__ __forceinline__ float sigm(float s) {
    return rcp_fast(1.0f + __expf(-s));
}

// Rare path: exact-zero member or full underflow in the check product.
// Implements the reference's skip-zero / any_nz extrinsic semantics.
__device__ __noinline__ float cn_fallback(float a, const float2 v01,
                                          const float2 v23, const float2 v45) {
    float vv[6] = {v01.x, v01.y, v23.x, v23.y, v45.x, v45.y};
    float P = 1.0f; int cz = 0;
    #pragma unroll
    for (int k = 0; k < 6; k++) {
        if (vv[k] == 0.0f) cz++; else P *= vv[k];
    }
    float ext;
    if (a != 0.0f) ext = (cz >= 5) ? 0.0f : P * rcp_fast(a);
    else           ext = (cz >= 6) ? 0.0f : P;
    ext = fminf(fmaxf(ext, -0.999999f), 0.999999f);
    return 0.6931472f * __log2f((1.0f + ext) * rcp_fast(1.0f - ext));
}

// Two-log CN form: ext = Q/a, 2*atanh(ext) = ln2*(log2|a+Q| - log2|a-Q|),
// clamped at +/-2*atanh(0.999999). a-+Q==0 -> +/-inf -> clamp (== ref clamp).
__device__ __forceinline__ float cn_edge(float a, float Q) {
    float t = 0.6931472f * (__log2f(fabsf(a + Q)) - __log2f(fabsf(a - Q)));
    return fminf(fmaxf(t, -TL_CLAMP), TL_CLAMP);
}

// ---------------------------------------------------------------------------
// Structure extraction (re-run every call; inputs restored pristine each time)
// M_out is [N,E] = M_ev.T: one nonzero (==1.0) per column e, at row var_of[e].
// Each var appears once per permutation layer (layer = e/NN) -> race-free.
// ---------------------------------------------------------------------------
__global__ __launch_bounds__(BS) void extract_struct(
    const float4* __restrict__ M_out4,
    int* __restrict__ var_of, int* __restrict__ varEdge) {
    int t = blockIdx.x * BS + threadIdx.x;
    if (t >= NN * EE / 4) return;
    float4 v = M_out4[t];
    int flat = t * 4;
    int n = flat / EE;
    int e = flat - n * EE;
    if (v.x != 0.0f) { var_of[e]     = n; varEdge[n * 3 + (e)     / NN] = e;     }
    if (v.y != 0.0f) { var_of[e + 1] = n; varEdge[n * 3 + (e + 1) / NN] = e + 1; }
    if (v.z != 0.0f) { var_of[e + 2] = n; varEdge[n * 3 + (e + 2) / NN] = e + 2; }
    if (v.w != 0.0f) { var_of[e + 3] = n; varEdge[n * 3 + (e + 3) / NN] = e + 3; }
}

// One thread per (matrix, edge): 2 scalar loads each (latency-parallel), plus
// NN threads for W9. Weights packed per PAIR as float4 (wAx,wAy,wBx,wBy) so
// bp_main loads one coalesced dwordx4 per pair per layer; nb packed as int4.
__global__ __launch_bounds__(BS) void extract_weights(
    const float* __restrict__ W1, const float* __restrict__ W3,
    const float* __restrict__ W5, const float* __restrict__ W7,
    const float* __restrict__ W9,
    const int* __restrict__ var_of, const int* __restrict__ varEdge,
    int4* __restrict__ nbq,
    float4* __restrict__ w1q, float4* __restrict__ w3q,
    float4* __restrict__ w5q, float4* __restrict__ w7q,
    float* __restrict__ w9v) {
    int t = blockIdx.x * BS + threadIdx.x;
    if (t < 4 * EE) {
        int m = t / EE;
        int e = t - m * EE;
        int n = var_of[e];
        int e0 = varEdge[3 * n], e1 = varEdge[3 * n + 1], e2 = varEdge[3 * n + 2];
        int ea, eb;
        if (e == e0)      { ea = e1; eb = e2; }
        else if (e == e1) { ea = e0; eb = e2; }
        else              { ea = e0; eb = e1; }
        const float* W = (m == 0) ? W1 : (m == 1) ? W3 : (m == 2) ? W5 : W7;
        size_t row = (size_t)e * EE;
        float2 w = make_float2(W[row + ea], W[row + eb]);
        float4* dq = (m == 0) ? w1q : (m == 1) ? w3q : (m == 2) ? w5q : w7q;
        ((float2*)dq)[e] = w;                       // half of pair e/2
        if (m == 0) ((int2*)nbq)[e] = make_int2(ea, eb);
    } else if (t < 4 * EE + NN) {
        int n = t - 4 * EE;
        #pragma unroll
        for (int k = 0; k < 3; k++) {
            int e = varEdge[3 * n + k];
            w9v[3 * n + k] = W9[(size_t)n * EE + e];
        }
    }
}

// ---------------------------------------------------------------------------
// Main BP kernel: one block per batch row, all state in LDS (18.1 KB -> 8/CU).
// Pair-granular: thread item = 2 consecutive edges (same check third).
// ---------------------------------------------------------------------------
__global__ __launch_bounds__(BS, 8) void bp_main(
    const float* __restrict__ x,
    const int2* __restrict__ var2,          // var_of viewed per pair
    const int* __restrict__ varEdge,
    const int4* __restrict__ nbq,
    const float4* __restrict__ w1q, const float4* __restrict__ w3q,
    const float4* __restrict__ w5q, const float4* __restrict__ w7q,
    const float* __restrict__ w9v,
    float* __restrict__ out) {
    __shared__ __align__(16) float llr_s[NN];
    __shared__ __align__(16) float te[EE];
    __shared__ __align__(16) float tl[EE];
    const int b = blockIdx.x;
    const int tid = threadIdx.x;

    const float* xr = x + (size_t)b * NN;
    for (int n = tid; n < NN; n += BS) llr_s[n] = xr[n];
    __syncthreads();

    // ---- per-thread loop-invariant state (registers) ----
    float2 lb[NP_IT];                       // llr at the pair's two variables
    int oA[NP_IT], oB[NP_IT], oC[NP_IT], oD[NP_IT];  // tl indices of neighbors
    int cOff[NP_IT];                        // float index of pair's check base
    #pragma unroll
    for (int i = 0; i < NP_IT; i++) {
        int p = tid + i * BS;
        if (p < NP) {
            int2 v = var2[p];
            lb[i] = make_float2(llr_s[v.x], llr_s[v.y]);
            int4 nn = nbq[p];
            oA[i] = nn.x; oB[i] = nn.y; oC[i] = nn.z; oD[i] = nn.w;
            cOff[i] = ((unsigned)p / 3u) * 6;
            // iteration 0: te = tanh(0.5 * llr[var_of[e]])
            *(float2*)(te + 2 * p) = make_float2(tanh_half(lb[i].x),
                                                 tanh_half(lb[i].y));
        } else {
            lb[i] = make_float2(0.f, 0.f);
            oA[i] = oB[i] = oC[i] = oD[i] = 0; cOff[i] = 0;
        }
    }
    // marg-out offsets (varEdge) cached; reused by the W9 epilogue too
    int m0[3], m1[3], m2[3];
    #pragma unroll
    for (int j = 0; j < 3; j++) {
        int n = tid + j * BS;
        if (n < NN) {
            m0[j] = varEdge[3 * n]; m1[j] = varEdge[3 * n + 1];
            m2[j] = varEdge[3 * n + 2];
        } else { m0[j] = m1[j] = m2[j] = 0; }
    }
    __syncthreads();

    // ---- CN pass (pair-granular) ----
    auto cn_pass = [&]() {
        #pragma unroll
        for (int i = 0; i < NP_IT; i++) {
            int p = tid + i * BS;
            if (p >= NP) break;
            const float2* ck = (const float2*)(te + cOff[i]);
            float2 v01 = ck[0], v23 = ck[1], v45 = ck[2];
            float2 a = *(const float2*)(te + 2 * p);
            float Q = ((v01.x * v01.y) * (v23.x * v23.y)) * (v45.x * v45.y);
            float t0, t1;
            if (__builtin_expect(Q != 0.0f, 1)) {
                t0 = cn_edge(a.x, Q);
                t1 = cn_edge(a.y, Q);
            } else {
                t0 = cn_fallback(a.x, v01, v23, v45);
                t1 = cn_fallback(a.y, v01, v23, v45);
            }
            *(float2*)(tl + 2 * p) = make_float2(t0, t1);
        }
    };
    auto marg_out = [&](float* dst) {
        #pragma unroll
        for (int j = 0; j < 3; j++) {
            int n = tid + j * BS;
            if (n < NN)
                dst[n] = sigm(llr_s[n] + tl[m0[j]] + tl[m1[j]] + tl[m2[j]]);
        }
    };

    cn_pass();
    __syncthreads();
    // out1 -> chunk 4 (return order: out5,out4,out3,out2,out1)
    marg_out(out + ((size_t)(4 * BATCH) + b) * NN);

    const float4* wqs[4] = {w1q, w3q, w5q, w7q};
    for (int L = 0; L < 4; L++) {
        const float4* __restrict__ wq = wqs[L];
        // VN update: pre = w*tl[nbrs] + llr;  te = tanh(pre/2)
        #pragma unroll
        for (int i = 0; i < NP_IT; i++) {
            int p = tid + i * BS;
            if (p < NP) {
                float4 w = wq[p];
                float preX = fmaf(w.x, tl[oA[i]], fmaf(w.y, tl[oB[i]], lb[i].x));
                float preY = fmaf(w.z, tl[oC[i]], fmaf(w.w, tl[oD[i]], lb[i].y));
                *(float2*)(te + 2 * p) = make_float2(tanh_half(preX),
                                                     tanh_half(preY));
            }
        }
        __syncthreads();   // te visible; also fences prior tl readers
        cn_pass();
        __syncthreads();
        if (L < 3) {
            // out2->chunk3, out3->chunk2, out4->chunk1
            marg_out(out + ((size_t)((3 - L) * BATCH) + b) * NN);
        } else {
            // out5 -> chunk 0: sigmoid(t@W9.T + llr)   (B4 = I)
            #pragma unroll
            for (int j = 0; j < 3; j++) {
                int n = tid + j * BS;
                if (n < NN) {
                    float s = llr_s[n]
                            + w9v[3 * n]     * tl[m0[j]]
                            + w9v[3 * n + 1] * tl[m1[j]]
                            + w9v[3 * n + 2] * tl[m2[j]];
                    out[(size_t)b * NN + n] = sigm(s);
                }
            }
        }
    }
}

// ---------------------------------------------------------------------------
extern "C" void kernel_launch(void* const* d_in, const int* in_sizes, int n_in,
                              void* d_out, int out_size, void* d_ws, size_t ws_size,
                              hipStream_t stream) {
    const float* x     = (const float*)d_in[0];
    const float* M_out = (const float*)d_in[3];
    const float* W1    = (const float*)d_in[5];
    const float* W3    = (const float*)d_in[6];
    const float* W5    = (const float*)d_in[7];
    const float* W7    = (const float*)d_in[8];
    const float* W9    = (const float*)d_in[9];
    // d_in[1]=M_first, d_in[2]=M_cn (patterns implied by check structure),
    // d_in[4]=bias_matrix (values 1.0), d_in[10..14]=B0..B4 (identity).
    float* out = (float*)d_out;

    char* ws = (char*)d_ws;                  // 16B-aligned base
    int4*   nbq     = (int4*)ws;   ws += NP * 16;
    float4* w1q     = (float4*)ws; ws += NP * 16;
    float4* w3q     = (float4*)ws; ws += NP * 16;
    float4* w5q     = (float4*)ws; ws += NP * 16;
    float4* w7q     = (float4*)ws; ws += NP * 16;
    int*    var_of  = (int*)ws;    ws += EE * 4;
    int*    varEdge = (int*)ws;    ws += NN * 3 * 4;
    float*  w9v     = (float*)ws;  ws += NN * 3 * 4;

    const int tot4 = NN * EE / 4;
    extract_struct<<<(tot4 + BS - 1) / BS, BS, 0, stream>>>(
        (const float4*)M_out, var_of, varEdge);
    const int totW = 4 * EE + NN;
    extract_weights<<<(totW + BS - 1) / BS, BS, 0, stream>>>(
        W1, W3, W5, W7, W9, var_of, varEdge, nbq, w1q, w3q, w5q, w7q, w9v);
    bp_main<<<BATCH, BS, 0, stream>>>(
        x, (const int2*)var_of, varEdge, nbq, w1q, w3q, w5q, w7q, w9v, out);
}

// Round 6
// 166.346 us; speedup vs baseline: 1.2336x; 1.0561x over previous
//
#include <hip/hip_runtime.h>
#include <math.h>

#define NN 648      // code length / variables
#define EE 1944     // edges
#define NCHK 324    // checks, each = 6 consecutive edges
#define BATCH 2048
#define BS 256      // extraction kernels
#define BSM 384     // bp_main: one check per thread (324 < 384), 6 waves
#define TL_CLAMP 14.508648f   // 2*atanh(0.999999)

// ---------------------------------------------------------------------------
// Fast transcendentals (hardware v_exp_f32 / v_log_f32 / v_rcp_f32).
// CRITICAL: tanh_half returns 0 IFF x==0 — zero-ness gates the reference's
// cn_update nz-mask semantics (R2 lesson: exp path flushes |x|<~2e-7 -> Taylor
// small path keeps tiny nonzeros nonzero).
// ---------------------------------------------------------------------------
__device__ __forceinline__ float rcp_fast(float x) { return __builtin_amdgcn_rcpf(x); }

__device__ __forceinline__ float tanh_half(float x) {
    // tanh(x/2) = 1 - 2/(e^x + 1): sign-correct, saturates exactly to +/-1.
    float E = __expf(x);
    float big = 1.0f - 2.0f * rcp_fast(E + 1.0f);
    float u = 0.5f * x;
    float small = u * (1.0f - 0.33333334f * u * u);   // |u|<=2^-6, err ~6e-10
    return (fabsf(x) < 0.03125f) ? small : big;
}

__device__ __forceinline__ float sigm(float s) {
    return rcp_fast(1.0f + __expf(-s));
}

// Two-log CN form: ext = Q/a, 2*atanh(ext) = ln2*(log2|a+Q| - log2|a-Q|),
// clamped at +/-2*atanh(0.999999). a-+Q==0 -> +/-inf -> clamp (== ref clamp).
__device__ __forceinline__ float cn_edge(float a, float Q) {
    float t = 0.6931472f * (__log2f(fabsf(a + Q)) - __log2f(fabsf(a - Q)));
    return fminf(fmaxf(t, -TL_CLAMP), TL_CLAMP);
}

// Rare path (exact-zero member / full underflow): reference skip-zero / any_nz
// extrinsic semantics. By-value args: no pointer to a register array (which
// would force scratch); __noinline__ keeps the hot path lean.
__device__ __noinline__ float cn_fallback(float a, float t0, float t1, float t2,
                                          float t3, float t4, float t5) {
    float vv[6] = {t0, t1, t2, t3, t4, t5};
    float P = 1.0f; int cz = 0;
    #pragma unroll
    for (int k = 0; k < 6; k++) {
        if (vv[k] == 0.0f) cz++; else P *= vv[k];
    }
    float ext;
    if (a != 0.0f) ext = (cz >= 5) ? 0.0f : P * rcp_fast(a);
    else           ext = (cz >= 6) ? 0.0f : P;
    ext = fminf(fmaxf(ext, -0.999999f), 0.999999f);
    return 0.6931472f * __log2f((1.0f + ext) * rcp_fast(1.0f - ext));
}

// ---------------------------------------------------------------------------
// Structure extraction (re-run every call; inputs restored pristine each time)
// M_out is [N,E] = M_ev.T: one nonzero (==1.0) per column e, at row var_of[e].
// Each var appears once per permutation layer (layer = e/NN) -> race-free.
// Also emits varc16[e] = var_of[e] as 16-bit (read as packed uint pairs).
// ---------------------------------------------------------------------------
__global__ __launch_bounds__(BS) void extract_struct(
    const float4* __restrict__ M_out4,
    int* __restrict__ var_of, int* __restrict__ varEdge,
    unsigned short* __restrict__ varc16) {
    int t = blockIdx.x * BS + threadIdx.x;
    if (t >= NN * EE / 4) return;
    float4 v = M_out4[t];
    int flat = t * 4;
    int n = flat / EE;
    int e = flat - n * EE;
    if (v.x != 0.0f) { var_of[e]     = n; varEdge[n*3 + (e)    /NN] = e;     varc16[e]     = (unsigned short)n; }
    if (v.y != 0.0f) { var_of[e + 1] = n; varEdge[n*3 + (e + 1)/NN] = e + 1; varc16[e + 1] = (unsigned short)n; }
    if (v.z != 0.0f) { var_of[e + 2] = n; varEdge[n*3 + (e + 2)/NN] = e + 2; varc16[e + 2] = (unsigned short)n; }
    if (v.w != 0.0f) { var_of[e + 3] = n; varEdge[n*3 + (e + 3)/NN] = e + 3; varc16[e + 3] = (unsigned short)n; }
}

// One thread per (matrix, edge): 2 scalar loads each, plus NN threads for W9.
// Weight layout per CHECK: 12 floats (2 per edge) = 3 float4 at float4-index
// 3c (float2-index == e, since edges are check-consecutive). nb packed as
// (eb<<16)|ea per edge.
__global__ __launch_bounds__(BS) void extract_weights(
    const float* __restrict__ W1, const float* __restrict__ W3,
    const float* __restrict__ W5, const float* __restrict__ W7,
    const float* __restrict__ W9,
    const int* __restrict__ var_of, const int* __restrict__ varEdge,
    unsigned* __restrict__ nb6,
    float4* __restrict__ w1q, float4* __restrict__ w3q,
    float4* __restrict__ w5q, float4* __restrict__ w7q,
    float* __restrict__ w9v) {
    int t = blockIdx.x * BS + threadIdx.x;
    if (t < 4 * EE) {
        int m = t / EE;
        int e = t - m * EE;
        int n = var_of[e];
        int e0 = varEdge[3 * n], e1 = varEdge[3 * n + 1], e2 = varEdge[3 * n + 2];
        int ea, eb;
        if (e == e0)      { ea = e1; eb = e2; }
        else if (e == e1) { ea = e0; eb = e2; }
        else              { ea = e0; eb = e1; }
        const float* W = (m == 0) ? W1 : (m == 1) ? W3 : (m == 2) ? W5 : W7;
        size_t row = (size_t)e * EE;
        float2 w = make_float2(W[row + ea], W[row + eb]);
        float4* dq = (m == 0) ? w1q : (m == 1) ? w3q : (m == 2) ? w5q : w7q;
        ((float2*)dq)[e] = w;
        if (m == 0) nb6[e] = (unsigned)ea | ((unsigned)eb << 16);
    } else if (t < 4 * EE + NN) {
        int n = t - 4 * EE;
        #pragma unroll
        for (int k = 0; k < 3; k++) {
            int e = varEdge[3 * n + k];
            w9v[3 * n + k] = W9[(size_t)n * EE + e];
        }
    }
}

// ---------------------------------------------------------------------------
// Main BP kernel: one block per batch row, ONE CHECK PER THREAD.
// All 6 check members (te) live in registers -> no te LDS array.
// tl double-buffered in LDS -> 1 barrier per layer (6 total).
// LDS: llr 2.6 KB + 2*tl 15.6 KB = 18.1 KB.
// ---------------------------------------------------------------------------
__global__ __launch_bounds__(BSM, 8) void bp_main(
    const float* __restrict__ x,
    const unsigned* __restrict__ varc,   // ushort[EE] viewed as uint[EE/2]
    const unsigned* __restrict__ nb6,    // uint[EE]: (eb<<16)|ea
    const int* __restrict__ varEdge,     // [3*NN]
    const float4* __restrict__ w1q, const float4* __restrict__ w3q,
    const float4* __restrict__ w5q, const float4* __restrict__ w7q,
    const float* __restrict__ w9v,
    float* __restrict__ out) {
    __shared__ __align__(16) float llr_s[NN];
    __shared__ __align__(16) float tlA[EE];
    __shared__ __align__(16) float tlB[EE];
    const int b = blockIdx.x;
    const int tid = threadIdx.x;

    // llr load: 324 float2, one iter (threads >= 324 idle here)
    {
        const float2* xr2 = (const float2*)(x + (size_t)b * NN);
        if (tid < NN / 2) ((float2*)llr_s)[tid] = xr2[tid];
    }
    __syncthreads();

    const bool ck = tid < NCHK;
    const int c = tid;
    float lb[6];        // llr at this check's 6 variables (loop-invariant)
    unsigned nbp[6];    // packed extrinsic same-var neighbor edge ids
    float te[6];        // check members — REGISTERS, never LDS

    if (ck) {
        #pragma unroll
        for (int j = 0; j < 3; j++) {
            unsigned vv = varc[3 * c + j];
            lb[2 * j]     = llr_s[vv & 0xffffu];
            lb[2 * j + 1] = llr_s[vv >> 16];
        }
        #pragma unroll
        for (int j = 0; j < 6; j++) {
            nbp[j] = nb6[6 * c + j];
            te[j] = tanh_half(lb[j]);   // iteration 0: te = tanh(0.5*llr[var])
        }
    }
    // marg-out offsets cached (also reused by W9 epilogue)
    int m0[2], m1[2], m2[2];
    #pragma unroll
    for (int j = 0; j < 2; j++) {
        int n = tid + j * BSM;
        if (n < NN) {
            m0[j] = varEdge[3 * n]; m1[j] = varEdge[3 * n + 1];
            m2[j] = varEdge[3 * n + 2];
        } else { m0[j] = m1[j] = m2[j] = 0; }
    }

    auto cn_store = [&](float* dst) {
        float Q = ((te[0] * te[1]) * (te[2] * te[3])) * (te[4] * te[5]);
        float* d = dst + 6 * c;
        if (__builtin_expect(Q != 0.0f, 1)) {
            #pragma unroll
            for (int j = 0; j < 6; j++) d[j] = cn_edge(te[j], Q);
        } else {
            #pragma unroll
            for (int j = 0; j < 6; j++)
                d[j] = cn_fallback(te[j], te[0], te[1], te[2], te[3], te[4], te[5]);
        }
    };
    auto marg = [&](const float* tl, float* dst) {
        #pragma unroll
        for (int j = 0; j < 2; j++) {
            int n = tid + j * BSM;
            if (n < NN)
                dst[n] = sigm(llr_s[n] + tl[m0[j]] + tl[m1[j]] + tl[m2[j]]);
        }
    };

    if (ck) cn_store(tlA);
    __syncthreads();
    // out1 -> chunk 4 (return order: out5,out4,out3,out2,out1)
    marg(tlA, out + ((size_t)(4 * BATCH) + b) * NN);

    const float4* wqs[4] = {w1q, w3q, w5q, w7q};
    #pragma unroll
    for (int L = 0; L < 4; L++) {
        const float4* __restrict__ wq = wqs[L];
        const float* tlc = (L & 1) ? tlB : tlA;   // CN_{L-1} output
        float* tln = (L & 1) ? tlA : tlB;         // CN_L output
        if (ck) {
            float4 wa = wq[3 * c], wb = wq[3 * c + 1], wc = wq[3 * c + 2];
            float w[12] = {wa.x, wa.y, wa.z, wa.w, wb.x, wb.y, wb.z, wb.w,
                           wc.x, wc.y, wc.z, wc.w};
            // VN: pre = w0*tl[ea] + w1*tl[eb] + llr[var]; te = tanh(pre/2)
            #pragma unroll
            for (int j = 0; j < 6; j++) {
                float pre = fmaf(w[2 * j], tlc[nbp[j] & 0xffffu],
                            fmaf(w[2 * j + 1], tlc[nbp[j] >> 16], lb[j]));
                te[j] = tanh_half(pre);
            }
            cn_store(tln);   // writes buffer nobody reads until next barrier
        }
        __syncthreads();
        if (L < 3) {
            // out2->chunk3, out3->chunk2, out4->chunk1
            marg(tln, out + ((size_t)((3 - L) * BATCH) + b) * NN);
        } else {
            // out5 -> chunk 0: sigmoid(t@W9.T + llr)   (B4 = I)
            #pragma unroll
            for (int j = 0; j < 2; j++) {
                int n = tid + j * BSM;
                if (n < NN) {
                    float s = llr_s[n]
                            + w9v[3 * n]     * tln[m0[j]]
                            + w9v[3 * n + 1] * tln[m1[j]]
                            + w9v[3 * n + 2] * tln[m2[j]];
                    out[(size_t)b * NN + n] = sigm(s);
                }
            }
        }
    }
}

// ---------------------------------------------------------------------------
extern "C" void kernel_launch(void* const* d_in, const int* in_sizes, int n_in,
                              void* d_out, int out_size, void* d_ws, size_t ws_size,
                              hipStream_t stream) {
    const float* x     = (const float*)d_in[0];
    const float* M_out = (const float*)d_in[3];
    const float* W1    = (const float*)d_in[5];
    const float* W3    = (const float*)d_in[6];
    const float* W5    = (const float*)d_in[7];
    const float* W7    = (const float*)d_in[8];
    const float* W9    = (const float*)d_in[9];
    // d_in[1]=M_first, d_in[2]=M_cn (patterns implied by check structure),
    // d_in[4]=bias_matrix (values 1.0), d_in[10..14]=B0..B4 (identity).
    float* out = (float*)d_out;

    char* ws = (char*)d_ws;                    // 16B-aligned base
    float4* w1q     = (float4*)ws;         ws += (EE / 2) * 16;
    float4* w3q     = (float4*)ws;         ws += (EE / 2) * 16;
    float4* w5q     = (float4*)ws;         ws += (EE / 2) * 16;
    float4* w7q     = (float4*)ws;         ws += (EE / 2) * 16;
    int*    var_of  = (int*)ws;            ws += EE * 4;
    int*    varEdge = (int*)ws;            ws += NN * 3 * 4;
    float*  w9v     = (float*)ws;          ws += NN * 3 * 4;
    unsigned* nb6   = (unsigned*)ws;       ws += EE * 4;
    unsigned short* varc16 = (unsigned short*)ws; ws += EE * 2;

    const int tot4 = NN * EE / 4;
    extract_struct<<<(tot4 + BS - 1) / BS, BS, 0, stream>>>(
        (const float4*)M_out, var_of, varEdge, varc16);
    const int totW = 4 * EE + NN;
    extract_weights<<<(totW + BS - 1) / BS, BS, 0, stream>>>(
        W1, W3, W5, W7, W9, var_of, varEdge, nb6, w1q, w3q, w5q, w7q, w9v);
    bp_main<<<BATCH, BSM, 0, stream>>>(
        x, (const unsigned*)varc16, nb6, varEdge, w1q, w3q, w5q, w7q, w9v, out);
}